// Round 5
// baseline (169.777 us; speedup 1.0000x reference)
//
#include <hip/hip_runtime.h>
#include <hip/hip_bf16.h>

#define NB 16
#define NT 2048
#define NC 256
#define NM (NB*NT)          // 32768 rows
#define NCH 16              // cumsum chunks
#define NCL (NT/NCH)        // 128 per chunk

typedef __attribute__((ext_vector_type(8))) short short8;
typedef __attribute__((ext_vector_type(4))) short short4v;
typedef __attribute__((ext_vector_type(4))) unsigned short ushort4v;
typedef __attribute__((ext_vector_type(4))) float f32x4;

__device__ __forceinline__ unsigned short f2bf(float x){
    union { float f; unsigned u; } v; v.f = x;
    unsigned r = v.u + 0x7FFFu + ((v.u >> 16) & 1u);   // RNE
    return (unsigned short)(r >> 16);
}
__device__ __forceinline__ float bf2f(unsigned short x){
    union { unsigned u; float f; } v; v.u = ((unsigned)x) << 16;
    return v.f;
}
__device__ __forceinline__ void gload16(const unsigned short* g, unsigned short* l){
    __builtin_amdgcn_global_load_lds((const __attribute__((address_space(1))) void*)g,
                                     (__attribute__((address_space(3))) void*)l, 16, 0, 0);
}

// Swizzle convention (chunk = 16B = 8 bf16), for LDS-staged operands only:
// physical col' = (col & ~63) | ((((col>>3)&7) ^ (row&7)) << 3) | (col & 7)
// Producers write physical; GEMMs global_load_lds linearly; ds_read XORs back.

// ---- prep: swizzled transposed bf16 weights + expanded Toeplitz A panels ----
// Aexp UNSWIZZLED (A is consumed via registers, not LDS):
// Aexp[Di][r][c] = tw[2047 + D - r + c], D = Di*64 - 1920, r<128, c<64.
__global__ void prep_kernel(const float* __restrict__ tw,
                            const float* __restrict__ Wk, const float* __restrict__ Wv,
                            const float* __restrict__ Wr, const float* __restrict__ Wo,
                            unsigned short* __restrict__ WkT, unsigned short* __restrict__ WvT,
                            unsigned short* __restrict__ WrT, unsigned short* __restrict__ WoT,
                            unsigned short* __restrict__ Aexp){
    int gid = blockIdx.x*256 + threadIdx.x;          // 65536 threads
    {
        int n = gid >> 8, u = gid & 255;
        int usw = (u & ~63) | ((((u>>3)&7) ^ (n&7)) << 3) | (u & 7);
        int src = u*NC + n;                           // WT[n][u] = W[u][n]
        WkT[n*NC + usw] = f2bf(Wk[src]);
        WvT[n*NC + usw] = f2bf(Wv[src]);
        WrT[n*NC + usw] = f2bf(Wr[src]);
        WoT[n*NC + usw] = f2bf(Wo[src]);
    }
    if (gid < 32768){
        int Di = gid >> 10, rem = gid & 1023;
        int r = rem >> 3, ql = rem & 7;
        int D = Di*64 - 1920;
        short8 vv;
        #pragma unroll
        for (int j = 0; j < 8; j++){
            int idx = 2047 + D - r + ql*8 + j;
            float val = (idx >= 0 && idx < NT) ? tw[idx] : 0.f;
            vv[j] = (short)f2bf(val);
        }
        *(short8*)&Aexp[(size_t)gid*8] = vv;
    }
}

// ---- time-shift mix -> xk/xv/xr (bf16, swizzled GEMM-A layout) ----
__global__ void mix_kernel(const float* __restrict__ x,
                           const float* __restrict__ tmk, const float* __restrict__ tmv,
                           const float* __restrict__ tmr,
                           unsigned short* __restrict__ xk, unsigned short* __restrict__ xv,
                           unsigned short* __restrict__ xr){
    int gid = blockIdx.x*256 + threadIdx.x;           // NM*NC/8
    int m = gid >> 5;
    int c0 = (gid & 31) << 3;
    int t = m & (NT-1);
    size_t base = (size_t)m*NC + c0;
    float xa[8], xb[8];
    #pragma unroll
    for (int j=0;j<8;j+=4) *(float4*)&xa[j] = *(const float4*)&x[base+j];
    if (t > 0) {
        #pragma unroll
        for (int j=0;j<8;j+=4) *(float4*)&xb[j] = *(const float4*)&x[base - NC + j];
    } else {
        #pragma unroll
        for (int j=0;j<8;j++) xb[j]=0.f;
    }
    short8 ok, ov, orr;
    #pragma unroll
    for (int j=0;j<8;j++){
        float mk = tmk[c0+j], mv = tmv[c0+j], mr = tmr[c0+j];
        ok[j]  = (short)f2bf(xa[j]*mk + xb[j]*(1.f-mk));
        ov[j]  = (short)f2bf(xa[j]*mv + xb[j]*(1.f-mv));
        orr[j] = (short)f2bf(xa[j]*mr + xb[j]*(1.f-mr));
    }
    int csw = (c0 & ~63) | ((((c0>>3)&7) ^ (m&7)) << 3);
    size_t dst = (size_t)m*NC + csw;
    *(short8*)&xk[dst] = ok;
    *(short8*)&xv[dst] = ov;
    *(short8*)&xr[dst] = orr;
}

// ---- 128x128-tile bf16 MFMA GEMM, [M,256]@[256,256] ----
// MODE 0: f32 plain out
// MODE 3: bf16 sigmoid plain out
// MODE 4: bf16 out TRANSPOSED [B][C][T] (for v)
// MODE 5: k-GEMM: f32 exp(clip) out + fused kv=k*v written to kvt [B][C][T] swizzled
template<int MODE>
__global__ __launch_bounds__(256) void gemm_c(const unsigned short* __restrict__ A,
                                              const unsigned short* __restrict__ BT,
                                              void* __restrict__ outp,
                                              const unsigned short* __restrict__ vbT,
                                              unsigned short* __restrict__ kvt){
    __shared__ unsigned short smem[32768];   // 64KB: As[2][8192] | Bs[2][8192]
    unsigned short* As0 = smem;
    unsigned short* Bs0 = smem + 16384;
    const int tid = threadIdx.x;
    const int lane = tid & 63, w = tid >> 6;
    const int wm = (w >> 1) * 64, wn = (w & 1) * 64;
    const int m0 = blockIdx.x * 128, n0 = blockIdx.y * 128;
    const int lrow = lane & 15, kgrp = lane >> 4, lx = lane & 7;
    const int qrow = tid >> 3, qc = tid & 7;

    f32x4 acc[4][4] = {};

    auto STAGE = [&](int buf, int k0){
        #pragma unroll
        for (int i=0;i<4;i++){
            int row = qrow + 32*i;
            int q = row*8 + qc;
            gload16(A  + (size_t)(m0+row)*NC + k0 + qc*8, As0 + buf*8192 + q*8);
            gload16(BT + (size_t)(n0+row)*NC + k0 + qc*8, Bs0 + buf*8192 + q*8);
        }
    };

    STAGE(0, 0);
    __syncthreads();
    for (int s = 0; s < 4; ++s){
        if (s < 3) STAGE((s+1)&1, (s+1)*64);
        const unsigned short* as = As0 + (s&1)*8192;
        const unsigned short* bs = Bs0 + (s&1)*8192;
        #pragma unroll
        for (int ks = 0; ks < 2; ++ks){
            const int lk = ks*4 + kgrp;
            const int ch = (lk ^ lx) << 3;
            short8 a[4], b[4];
            #pragma unroll
            for (int mi=0;mi<4;mi++) a[mi] = *(const short8*)&as[(wm + mi*16 + lrow)*64 + ch];
            #pragma unroll
            for (int ni=0;ni<4;ni++) b[ni] = *(const short8*)&bs[(wn + ni*16 + lrow)*64 + ch];
            #pragma unroll
            for (int mi=0;mi<4;mi++)
            #pragma unroll
            for (int ni=0;ni<4;ni++)
                acc[mi][ni] = __builtin_amdgcn_mfma_f32_16x16x32_bf16(a[mi], b[ni], acc[mi][ni], 0,0,0);
        }
        __syncthreads();
    }

    const int orow = wm + kgrp*4;      // local row base
    const int ocol = wn + lrow;        // local col base
    if (MODE == 0 || MODE == 3){
        #pragma unroll
        for (int mi=0;mi<4;mi++)
        #pragma unroll
        for (int ni=0;ni<4;ni++)
        #pragma unroll
        for (int i=0;i<4;i++){
            float vv = acc[mi][ni][i];
            size_t off = (size_t)(m0 + orow + mi*16 + i)*NC + n0 + ocol + ni*16;
            if (MODE == 0) ((float*)outp)[off] = vv;
            if (MODE == 3) ((unsigned short*)outp)[off] = f2bf(1.f/(1.f+__expf(-vv)));
        }
    } else {
        const int b = m0 >> 11, t0b = m0 & 2047;
        unsigned short (*tileT)[136] = (unsigned short (*)[136])smem;  // [c 128][t 128+8]
        #pragma unroll
        for (int mi=0;mi<4;mi++)
        #pragma unroll
        for (int ni=0;ni<4;ni++){
            const int cL = ocol + ni*16;      // local c
            const int t4 = orow + mi*16;      // local t (4 consecutive)
            short4v pk;
            if (MODE == 5){
                ushort4v v4 = *(const ushort4v*)&vbT[((size_t)(b*NC + n0 + cL))*NT + t0b + t4];
                #pragma unroll
                for (int i=0;i<4;i++){
                    float ke = __expf(fminf(fmaxf(acc[mi][ni][i],-60.f),30.f));
                    ((float*)outp)[(size_t)(m0 + t4 + i)*NC + n0 + cL] = ke;
                    pk[i] = (short)f2bf(ke * bf2f(v4[i]));
                }
            } else {
                #pragma unroll
                for (int i=0;i<4;i++) pk[i] = (short)f2bf(acc[mi][ni][i]);
            }
            *(short4v*)&tileT[cL][t4] = pk;
        }
        __syncthreads();
        #pragma unroll
        for (int p=0;p<8;p++){
            int c = (tid >> 4) + p*16;
            int t8 = (tid & 15) * 8;
            short8 vv = *(const short8*)&tileT[c][t8];
            if (MODE == 4){
                *(short8*)&((unsigned short*)outp)[((size_t)(b*NC + n0 + c))*NT + t0b + t8] = vv;
            } else {
                int row = n0 + c;
                int colp = (t8 & ~63) | ((((t8>>3)&7) ^ (row&7)) << 3);
                *(short8*)&kvt[((size_t)(b*NC + row))*NT + t0b + colp] = vv;
            }
        }
    }
}

// ---- cumsum of k over T ----
__global__ void scan1(const float* __restrict__ kf, float* __restrict__ part){
    int gid = blockIdx.x*256 + threadIdx.x;  // B*NCH*C = 65536
    int c = gid & 255, ch = (gid >> 8) & 15, b = gid >> 12;
    const float* p = kf + ((size_t)b*NT + ch*NCL)*NC + c;
    float s = 0.f;
    for (int i=0;i<NCL;i++) s += p[(size_t)i*NC];
    part[gid] = s;
}
__global__ void scan2(const float* __restrict__ kf, const float* __restrict__ part,
                      float* __restrict__ sumk){
    int gid = blockIdx.x*256 + threadIdx.x;
    int c = gid & 255, ch = (gid >> 8) & 15, b = gid >> 12;
    float off = 0.f;
    for (int j=0;j<ch;j++) off += part[((b*NCH + j)<<8) + c];
    const float* p = kf + ((size_t)b*NT + ch*NCL)*NC + c;
    float* o = sumk + ((size_t)b*NT + ch*NCL)*NC + c;
    float s = off;
    for (int i=0;i<NCL;i++){ s += p[(size_t)i*NC]; o[(size_t)i*NC] = s; }
}

// ---- wkv = Toeplitz @ kv: BK=128, A from global->registers, B via LDS ----
__global__ __launch_bounds__(256) void gemm_wkv(const unsigned short* __restrict__ Aexp,
                                                const unsigned short* __restrict__ kvt,
                                                const unsigned short* __restrict__ srb,
                                                const float* __restrict__ sumk,
                                                unsigned short* __restrict__ rout){
    __shared__ unsigned short Bs[2][64*128];   // 2 x 16KB
    const int tid = threadIdx.x;
    const int lane = tid & 63, w = tid >> 6;
    const int wm = (w >> 1) * 64, wn = (w & 1) * 32;   // wave tile 64x32
    const int lrow = lane & 15, kgrp = lane >> 4;

    // pairing: blocks id and id+512 co-CU, workloads sum to 17 steps
    const int id = blockIdx.x;                 // 1024 blocks
    const int j = id & 511, hi = id >> 9;
    const int t_idx = hi ? 15 - (j >> 5) : (j >> 5);
    const int combo = (j & 31) | (hi << 5);    // 0..63
    const int b  = combo >> 2;
    const int c0 = (combo & 3) * 64;
    const int t0 = t_idx * 128;
    const int nsteps = t_idx + 1;              // BK=128 steps
    const unsigned short* Ab = Aexp + (size_t)(30 - 2*t_idx)*8192;  // panel P0

    f32x4 acc[4][2] = {};

    auto STAGE = [&](int buf, int s){
        const int u0 = s*128;
        #pragma unroll
        for (int i=0;i<4;i++){
            int idx = (w*4 + i)*64 + lane;     // chunk 0..1023 (row*16 + cp)
            int row = idx >> 4, cp = idx & 15;
            gload16(kvt + ((size_t)(b*NC + c0 + row))*NT + u0 + cp*8, &Bs[buf][0] + (size_t)idx*8);
        }
    };

    STAGE(0, 0);
    __syncthreads();
    for (int s = 0; s < nsteps; ++s){
        if (s+1 < nsteps) STAGE((s+1)&1, s+1);
        const unsigned short* bs = &Bs[s&1][0];
        const unsigned short* ap = Ab + (size_t)s*16384;   // 2 panels (32KB) per step
        #pragma unroll
        for (int ks = 0; ks < 4; ++ks){
            const int kc = ks*4 + kgrp;                    // k-chunk 0..15
            short8 a[4], b8[2];
            #pragma unroll
            for (int mi=0;mi<4;mi++)
                a[mi] = *(const short8*)&ap[(size_t)(kc>>3)*8192 + (wm + mi*16 + lrow)*64 + (kc&7)*8];
            const int cph = ((kc & 8) | ((kc & 7) ^ (lrow & 7))) << 3;   // physical chunk*8
            #pragma unroll
            for (int ni=0;ni<2;ni++)
                b8[ni] = *(const short8*)&bs[(wn + ni*16 + lrow)*128 + cph];
            #pragma unroll
            for (int mi=0;mi<4;mi++)
            #pragma unroll
            for (int ni=0;ni<2;ni++)
                acc[mi][ni] = __builtin_amdgcn_mfma_f32_16x16x32_bf16(a[mi], b8[ni], acc[mi][ni], 0,0,0);
        }
        __syncthreads();
    }

    const int orow = wm + kgrp*4;
    const int ocol = c0 + wn + lrow;
    #pragma unroll
    for (int mi=0;mi<4;mi++)
    #pragma unroll
    for (int ni=0;ni<2;ni++)
    #pragma unroll
    for (int i=0;i<4;i++){
        int t = t0 + orow + mi*16 + i;
        int col = ocol + ni*16;
        size_t g = (size_t)(b*NT + t)*NC + col;
        float sr = bf2f(srb[g]);
        float sk = sumk[g];
        float vv = sr * acc[mi][ni][i] / sk;
        int csw = (col & ~63) | ((((col>>3)&7) ^ (t&7)) << 3) | (col & 7);
        rout[(size_t)(b*NT + t)*NC + csw] = f2bf(vv);
    }
}

extern "C" void kernel_launch(void* const* d_in, const int* in_sizes, int n_in,
                              void* d_out, int out_size, void* d_ws, size_t ws_size,
                              hipStream_t stream) {
    const float* x   = (const float*)d_in[0];
    const float* tw  = (const float*)d_in[1];
    const float* tmk = (const float*)d_in[2];
    const float* tmv = (const float*)d_in[3];
    const float* tmr = (const float*)d_in[4];
    const float* Wk  = (const float*)d_in[5];
    const float* Wv  = (const float*)d_in[6];
    const float* Wr  = (const float*)d_in[7];
    const float* Wo  = (const float*)d_in[8];

    char* ws = (char*)d_ws;
    const size_t MC = (size_t)NM*NC;   // 8,388,608
    unsigned short* xk   = (unsigned short*)(ws);             // bf16 MC (swz)
    unsigned short* xv   = (unsigned short*)(ws + MC*2);      // bf16 MC (swz)
    unsigned short* xr   = (unsigned short*)(ws + MC*4);      // bf16 MC (swz)
    float*          kf   = (float*)(ws + MC*6);               // f32 MC
    unsigned short* vbT  = (unsigned short*)(ws + MC*10);     // bf16 MC, [B][C][T]
    unsigned short* srb  = (unsigned short*)(ws + MC*12);     // bf16 MC (sigmoid r)
    float*          sumk = (float*)(ws + MC*14);              // f32 MC
    unsigned short* kvt  = (unsigned short*)(ws + MC*18);     // bf16 MC (swz, [B][C][T])
    unsigned short* Aexp = (unsigned short*)(ws + MC*20);     // 512KB
    unsigned short* WkT  = (unsigned short*)(ws + MC*20 + 524288);
    unsigned short* WvT  = WkT + NC*NC;
    unsigned short* WrT  = WvT + NC*NC;
    unsigned short* WoT  = WrT + NC*NC;
    float*          part = (float*)(ws + MC*20 + 1048576);    // 256KB
    unsigned short* rwkvb = xk;   // xk dead after k-GEMM

    prep_kernel<<<256,256,0,stream>>>(tw, Wk,Wv,Wr,Wo, WkT,WvT,WrT,WoT, Aexp);
    mix_kernel<<<(int)(MC/8/256),256,0,stream>>>(x,tmk,tmv,tmr,xk,xv,xr);
    gemm_c<4><<<dim3(NM/128,NC/128),256,0,stream>>>(xv,WvT,vbT,nullptr,nullptr);
    gemm_c<5><<<dim3(NM/128,NC/128),256,0,stream>>>(xk,WkT,kf,vbT,kvt);
    gemm_c<3><<<dim3(NM/128,NC/128),256,0,stream>>>(xr,WrT,srb,nullptr,nullptr);
    scan1<<<256,256,0,stream>>>(kf,part);
    scan2<<<256,256,0,stream>>>(kf,part,sumk);
    gemm_wkv<<<1024,256,0,stream>>>(Aexp,kvt,srb,sumk,rwkvb);
    gemm_c<0><<<dim3(NM/128,NC/128),256,0,stream>>>(rwkvb,WoT,(float*)d_out,nullptr,nullptr);
}

// Round 6
// 130.466 us; speedup vs baseline: 1.3013x; 1.3013x over previous
//
#include <hip/hip_runtime.h>
#include <hip/hip_bf16.h>

#define NB 16
#define NT 2048
#define NC 256
#define NM (NB*NT)          // 32768 rows
#define NCH 16              // cumsum chunks
#define NCL (NT/NCH)        // 128 per chunk

typedef __attribute__((ext_vector_type(8))) short short8;
typedef __attribute__((ext_vector_type(4))) short short4v;
typedef __attribute__((ext_vector_type(4))) unsigned short ushort4v;
typedef __attribute__((ext_vector_type(4))) float f32x4;

__device__ __forceinline__ unsigned short f2bf(float x){
    union { float f; unsigned u; } v; v.f = x;
    unsigned r = v.u + 0x7FFFu + ((v.u >> 16) & 1u);   // RNE
    return (unsigned short)(r >> 16);
}
__device__ __forceinline__ float bf2f(unsigned short x){
    union { unsigned u; float f; } v; v.u = ((unsigned)x) << 16;
    return v.f;
}
__device__ __forceinline__ void gload16(const unsigned short* g, unsigned short* l){
    __builtin_amdgcn_global_load_lds((const __attribute__((address_space(1))) void*)g,
                                     (__attribute__((address_space(3))) void*)l, 16, 0, 0);
}

// Swizzle convention (chunk = 16B = 8 bf16):
// physical col' = (col & ~63) | ((((col>>3)&7) ^ (row&7)) << 3) | (col & 7)
// Producers write physical; GEMMs global_load_lds linearly; ds_read XORs back.

// ---- prep: swizzled transposed bf16 weights + expanded Toeplitz A panels ----
// Aexp[Di][r][ql] swizzled: content at physical chunk ql is logical chunk ql^(r&7);
// logical A[r][c] = tw[2047 + D - r + c], D = Di*64 - 1920.
__global__ void prep_kernel(const float* __restrict__ tw,
                            const float* __restrict__ Wk, const float* __restrict__ Wv,
                            const float* __restrict__ Wr, const float* __restrict__ Wo,
                            unsigned short* __restrict__ WkT, unsigned short* __restrict__ WvT,
                            unsigned short* __restrict__ WrT, unsigned short* __restrict__ WoT,
                            unsigned short* __restrict__ Aexp){
    int gid = blockIdx.x*256 + threadIdx.x;          // 65536 threads
    {
        int n = gid >> 8, u = gid & 255;
        int usw = (u & ~63) | ((((u>>3)&7) ^ (n&7)) << 3) | (u & 7);
        int src = u*NC + n;                           // WT[n][u] = W[u][n]
        WkT[n*NC + usw] = f2bf(Wk[src]);
        WvT[n*NC + usw] = f2bf(Wv[src]);
        WrT[n*NC + usw] = f2bf(Wr[src]);
        WoT[n*NC + usw] = f2bf(Wo[src]);
    }
    if (gid < 32768){
        int Di = gid >> 10, rem = gid & 1023;
        int r = rem >> 3, ql = rem & 7;
        int qlog = ql ^ (r & 7);
        int D = Di*64 - 1920;
        short8 vv;
        #pragma unroll
        for (int j = 0; j < 8; j++){
            int idx = 2047 + D - r + qlog*8 + j;
            float val = (idx >= 0 && idx < NT) ? tw[idx] : 0.f;
            vv[j] = (short)f2bf(val);
        }
        *(short8*)&Aexp[(size_t)gid*8] = vv;
    }
}

// ---- time-shift mix -> xk/xv/xr (bf16, swizzled GEMM-A layout) ----
__global__ void mix_kernel(const float* __restrict__ x,
                           const float* __restrict__ tmk, const float* __restrict__ tmv,
                           const float* __restrict__ tmr,
                           unsigned short* __restrict__ xk, unsigned short* __restrict__ xv,
                           unsigned short* __restrict__ xr){
    int gid = blockIdx.x*256 + threadIdx.x;           // NM*NC/8
    int m = gid >> 5;
    int c0 = (gid & 31) << 3;
    int t = m & (NT-1);
    size_t base = (size_t)m*NC + c0;
    float xa[8], xb[8];
    #pragma unroll
    for (int j=0;j<8;j+=4) *(float4*)&xa[j] = *(const float4*)&x[base+j];
    if (t > 0) {
        #pragma unroll
        for (int j=0;j<8;j+=4) *(float4*)&xb[j] = *(const float4*)&x[base - NC + j];
    } else {
        #pragma unroll
        for (int j=0;j<8;j++) xb[j]=0.f;
    }
    short8 ok, ov, orr;
    #pragma unroll
    for (int j=0;j<8;j++){
        float mk = tmk[c0+j], mv = tmv[c0+j], mr = tmr[c0+j];
        ok[j]  = (short)f2bf(xa[j]*mk + xb[j]*(1.f-mk));
        ov[j]  = (short)f2bf(xa[j]*mv + xb[j]*(1.f-mv));
        orr[j] = (short)f2bf(xa[j]*mr + xb[j]*(1.f-mr));
    }
    int csw = (c0 & ~63) | ((((c0>>3)&7) ^ (m&7)) << 3);
    size_t dst = (size_t)m*NC + csw;
    *(short8*)&xk[dst] = ok;
    *(short8*)&xv[dst] = ov;
    *(short8*)&xr[dst] = orr;
}

// ---- 128x128-tile bf16 MFMA GEMM, [M,256]@[256,256], counted-vmcnt pipeline ----
// MODE 0: f32 plain out
// MODE 3: bf16 sigmoid plain out
// MODE 4: bf16 out TRANSPOSED [B][C][T] (for v)
// MODE 5: k-GEMM: f32 exp(clip) out + fused kv=k*v written to kvt [B][C][T] swizzled
template<int MODE>
__global__ __launch_bounds__(256) void gemm_c(const unsigned short* __restrict__ A,
                                              const unsigned short* __restrict__ BT,
                                              void* __restrict__ outp,
                                              const unsigned short* __restrict__ vbT,
                                              unsigned short* __restrict__ kvt){
    __shared__ unsigned short smem[32768];   // 64KB: As[2][8192] | Bs[2][8192]
    unsigned short* As0 = smem;
    unsigned short* Bs0 = smem + 16384;
    const int tid = threadIdx.x;
    const int lane = tid & 63, w = tid >> 6;
    const int wm = (w >> 1) * 64, wn = (w & 1) * 64;
    const int m0 = blockIdx.x * 128, n0 = blockIdx.y * 128;
    const int lrow = lane & 15, kgrp = lane >> 4, lx = lane & 7;
    const int qrow = tid >> 3, qc = tid & 7;

    f32x4 acc[4][4] = {};

    auto STAGE = [&](int buf, int k0){
        #pragma unroll
        for (int i=0;i<4;i++){
            int row = qrow + 32*i;
            int q = row*8 + qc;
            gload16(A  + (size_t)(m0+row)*NC + k0 + qc*8, As0 + buf*8192 + q*8);
            gload16(BT + (size_t)(n0+row)*NC + k0 + qc*8, Bs0 + buf*8192 + q*8);
        }
    };

    STAGE(0, 0);
    for (int s = 0; s < 4; ++s){
        if (s < 3){
            STAGE((s+1)&1, (s+1)*64);                      // 8 loads in flight for next buf
            asm volatile("s_waitcnt vmcnt(8)" ::: "memory"); // wait only for CURRENT buf's 8
        } else {
            asm volatile("s_waitcnt vmcnt(0)" ::: "memory");
        }
        __builtin_amdgcn_s_barrier();
        const unsigned short* as = As0 + (s&1)*8192;
        const unsigned short* bs = Bs0 + (s&1)*8192;
        __builtin_amdgcn_s_setprio(1);
        #pragma unroll
        for (int ks = 0; ks < 2; ++ks){
            const int lk = ks*4 + kgrp;
            const int ch = (lk ^ lx) << 3;
            short8 a[4], b[4];
            #pragma unroll
            for (int mi=0;mi<4;mi++) a[mi] = *(const short8*)&as[(wm + mi*16 + lrow)*64 + ch];
            #pragma unroll
            for (int ni=0;ni<4;ni++) b[ni] = *(const short8*)&bs[(wn + ni*16 + lrow)*64 + ch];
            #pragma unroll
            for (int mi=0;mi<4;mi++)
            #pragma unroll
            for (int ni=0;ni<4;ni++)
                acc[mi][ni] = __builtin_amdgcn_mfma_f32_16x16x32_bf16(a[mi], b[ni], acc[mi][ni], 0,0,0);
        }
        __builtin_amdgcn_s_setprio(0);
        __builtin_amdgcn_s_barrier();
    }

    const int orow = wm + kgrp*4;      // local row base
    const int ocol = wn + lrow;        // local col base
    if (MODE == 0 || MODE == 3){
        #pragma unroll
        for (int mi=0;mi<4;mi++)
        #pragma unroll
        for (int ni=0;ni<4;ni++)
        #pragma unroll
        for (int i=0;i<4;i++){
            float vv = acc[mi][ni][i];
            size_t off = (size_t)(m0 + orow + mi*16 + i)*NC + n0 + ocol + ni*16;
            if (MODE == 0) ((float*)outp)[off] = vv;
            if (MODE == 3) ((unsigned short*)outp)[off] = f2bf(1.f/(1.f+__expf(-vv)));
        }
    } else {
        const int b = m0 >> 11, t0b = m0 & 2047;
        unsigned short (*tileT)[136] = (unsigned short (*)[136])smem;  // [c 128][t 128+8]
        #pragma unroll
        for (int mi=0;mi<4;mi++)
        #pragma unroll
        for (int ni=0;ni<4;ni++){
            const int cL = ocol + ni*16;      // local c
            const int t4 = orow + mi*16;      // local t (4 consecutive)
            short4v pk;
            if (MODE == 5){
                ushort4v v4 = *(const ushort4v*)&vbT[((size_t)(b*NC + n0 + cL))*NT + t0b + t4];
                #pragma unroll
                for (int i=0;i<4;i++){
                    float ke = __expf(fminf(fmaxf(acc[mi][ni][i],-60.f),30.f));
                    ((float*)outp)[(size_t)(m0 + t4 + i)*NC + n0 + cL] = ke;
                    pk[i] = (short)f2bf(ke * bf2f(v4[i]));
                }
            } else {
                #pragma unroll
                for (int i=0;i<4;i++) pk[i] = (short)f2bf(acc[mi][ni][i]);
            }
            *(short4v*)&tileT[cL][t4] = pk;
        }
        __syncthreads();
        #pragma unroll
        for (int p=0;p<8;p++){
            int c = (tid >> 4) + p*16;
            int t8 = (tid & 15) * 8;
            short8 vv = *(const short8*)&tileT[c][t8];
            if (MODE == 4){
                *(short8*)&((unsigned short*)outp)[((size_t)(b*NC + n0 + c))*NT + t0b + t8] = vv;
            } else {
                int row = n0 + c;
                int colp = (t8 & ~63) | ((((t8>>3)&7) ^ (row&7)) << 3);
                *(short8*)&kvt[((size_t)(b*NC + row))*NT + t0b + colp] = vv;
            }
        }
    }
}

// ---- cumsum of k over T ----
__global__ void scan1(const float* __restrict__ kf, float* __restrict__ part){
    int gid = blockIdx.x*256 + threadIdx.x;  // B*NCH*C = 65536
    int c = gid & 255, ch = (gid >> 8) & 15, b = gid >> 12;
    const float* p = kf + ((size_t)b*NT + ch*NCL)*NC + c;
    float s = 0.f;
    for (int i=0;i<NCL;i++) s += p[(size_t)i*NC];
    part[gid] = s;
}
__global__ void scan2(const float* __restrict__ kf, const float* __restrict__ part,
                      float* __restrict__ sumk){
    int gid = blockIdx.x*256 + threadIdx.x;
    int c = gid & 255, ch = (gid >> 8) & 15, b = gid >> 12;
    float off = 0.f;
    for (int j=0;j<ch;j++) off += part[((b*NCH + j)<<8) + c];
    const float* p = kf + ((size_t)b*NT + ch*NCL)*NC + c;
    float* o = sumk + ((size_t)b*NT + ch*NCL)*NC + c;
    float s = off;
    for (int i=0;i<NCL;i++){ s += p[(size_t)i*NC]; o[(size_t)i*NC] = s; }
}

// ---- wkv = Toeplitz @ kv, 128t x 64c tiles, counted-vmcnt pipeline ----
__global__ __launch_bounds__(256) void gemm_wkv(const unsigned short* __restrict__ Aexp,
                                                const unsigned short* __restrict__ kvt,
                                                const unsigned short* __restrict__ srb,
                                                const float* __restrict__ sumk,
                                                unsigned short* __restrict__ rout){
    __shared__ unsigned short As[2][128*64];   // 32KB
    __shared__ unsigned short Bs[2][64*64];    // 16KB
    const int tid = threadIdx.x;
    const int lane = tid & 63, w = tid >> 6;
    const int wm = (w >> 1) * 64, wn = (w & 1) * 32;   // wave tile 64x32
    const int lrow = lane & 15, kgrp = lane >> 4, lx = lane & 7;
    const int qrow = tid >> 3, qc = tid & 7;

    // pairing: blocks id and id+512 co-CU, workloads sum to 36 steps
    const int id = blockIdx.x;                 // 1024 blocks
    const int j = id & 511, hi = id >> 9;
    const int t_idx = hi ? 15 - (j >> 5) : (j >> 5);
    const int combo = (j & 31) | (hi << 5);    // 0..63
    const int b  = combo >> 2;
    const int c0 = (combo & 3) * 64;
    const int t0 = t_idx * 128;
    const int nsteps = 2*t_idx + 2;
    const unsigned short* Ab = Aexp + (size_t)(30 - 2*t_idx)*8192;

    f32x4 acc[4][2] = {};

    auto STAGE = [&](int buf, int s){
        const int u0 = s*64;
        #pragma unroll
        for (int i=0;i<4;i++){
            int row = qrow + 32*i;
            gload16(Ab + (size_t)s*8192 + (size_t)(row*8+qc)*8, &As[buf][(row*8+qc)*8]);
        }
        #pragma unroll
        for (int i=0;i<2;i++){
            int row = qrow + 32*i;
            gload16(kvt + ((size_t)(b*NC + c0 + row))*NT + u0 + qc*8, &Bs[buf][(row*8+qc)*8]);
        }
    };

    STAGE(0, 0);
    for (int s = 0; s < nsteps; ++s){
        if (s+1 < nsteps){
            STAGE((s+1)&1, s+1);                            // 6 loads for next buf
            asm volatile("s_waitcnt vmcnt(6)" ::: "memory"); // wait only for CURRENT buf's 6
        } else {
            asm volatile("s_waitcnt vmcnt(0)" ::: "memory");
        }
        __builtin_amdgcn_s_barrier();
        const unsigned short* as = As[s&1];
        const unsigned short* bs = Bs[s&1];
        __builtin_amdgcn_s_setprio(1);
        #pragma unroll
        for (int ks = 0; ks < 2; ++ks){
            const int lk = ks*4 + kgrp;
            const int ch = (lk ^ lx) << 3;
            short8 a[4], b8[2];
            #pragma unroll
            for (int mi=0;mi<4;mi++) a[mi]  = *(const short8*)&as[(wm + mi*16 + lrow)*64 + ch];
            #pragma unroll
            for (int ni=0;ni<2;ni++) b8[ni] = *(const short8*)&bs[(wn + ni*16 + lrow)*64 + ch];
            #pragma unroll
            for (int mi=0;mi<4;mi++)
            #pragma unroll
            for (int ni=0;ni<2;ni++)
                acc[mi][ni] = __builtin_amdgcn_mfma_f32_16x16x32_bf16(a[mi], b8[ni], acc[mi][ni], 0,0,0);
        }
        __builtin_amdgcn_s_setprio(0);
        __builtin_amdgcn_s_barrier();
    }

    const int orow = wm + kgrp*4;
    const int ocol = c0 + wn + lrow;
    #pragma unroll
    for (int mi=0;mi<4;mi++)
    #pragma unroll
    for (int ni=0;ni<2;ni++)
    #pragma unroll
    for (int i=0;i<4;i++){
        int t = t0 + orow + mi*16 + i;
        int col = ocol + ni*16;
        size_t g = (size_t)(b*NT + t)*NC + col;
        float sr = bf2f(srb[g]);
        float sk = sumk[g];
        float vv = sr * acc[mi][ni][i] / sk;
        int csw = (col & ~63) | ((((col>>3)&7) ^ (t&7)) << 3) | (col & 7);
        rout[(size_t)(b*NT + t)*NC + csw] = f2bf(vv);
    }
}

extern "C" void kernel_launch(void* const* d_in, const int* in_sizes, int n_in,
                              void* d_out, int out_size, void* d_ws, size_t ws_size,
                              hipStream_t stream) {
    const float* x   = (const float*)d_in[0];
    const float* tw  = (const float*)d_in[1];
    const float* tmk = (const float*)d_in[2];
    const float* tmv = (const float*)d_in[3];
    const float* tmr = (const float*)d_in[4];
    const float* Wk  = (const float*)d_in[5];
    const float* Wv  = (const float*)d_in[6];
    const float* Wr  = (const float*)d_in[7];
    const float* Wo  = (const float*)d_in[8];

    char* ws = (char*)d_ws;
    const size_t MC = (size_t)NM*NC;   // 8,388,608
    unsigned short* xk   = (unsigned short*)(ws);             // bf16 MC (swz)
    unsigned short* xv   = (unsigned short*)(ws + MC*2);      // bf16 MC (swz)
    unsigned short* xr   = (unsigned short*)(ws + MC*4);      // bf16 MC (swz)
    float*          kf   = (float*)(ws + MC*6);               // f32 MC
    unsigned short* vbT  = (unsigned short*)(ws + MC*10);     // bf16 MC, [B][C][T]
    unsigned short* srb  = (unsigned short*)(ws + MC*12);     // bf16 MC (sigmoid r)
    float*          sumk = (float*)(ws + MC*14);              // f32 MC
    unsigned short* kvt  = (unsigned short*)(ws + MC*18);     // bf16 MC (swz, [B][C][T])
    unsigned short* Aexp = (unsigned short*)(ws + MC*20);     // 512KB
    unsigned short* WkT  = (unsigned short*)(ws + MC*20 + 524288);
    unsigned short* WvT  = WkT + NC*NC;
    unsigned short* WrT  = WvT + NC*NC;
    unsigned short* WoT  = WrT + NC*NC;
    float*          part = (float*)(ws + MC*20 + 1048576);    // 256KB
    unsigned short* rwkvb = xk;   // xk dead after k-GEMM

    prep_kernel<<<256,256,0,stream>>>(tw, Wk,Wv,Wr,Wo, WkT,WvT,WrT,WoT, Aexp);
    mix_kernel<<<(int)(MC/8/256),256,0,stream>>>(x,tmk,tmv,tmr,xk,xv,xr);
    gemm_c<4><<<dim3(NM/128,NC/128),256,0,stream>>>(xv,WvT,vbT,nullptr,nullptr);
    gemm_c<5><<<dim3(NM/128,NC/128),256,0,stream>>>(xk,WkT,kf,vbT,kvt);
    gemm_c<3><<<dim3(NM/128,NC/128),256,0,stream>>>(xr,WrT,srb,nullptr,nullptr);
    scan1<<<256,256,0,stream>>>(kf,part);
    scan2<<<256,256,0,stream>>>(kf,part,sumk);
    gemm_wkv<<<1024,256,0,stream>>>(Aexp,kvt,srb,sumk,rwkvb);
    gemm_c<0><<<dim3(NM/128,NC/128),256,0,stream>>>(rwkvb,WoT,(float*)d_out,nullptr,nullptr);
}